// Round 10
// baseline (188.198 us; speedup 1.0000x reference)
//
#include <hip/hip_runtime.h>
#include <math.h>

#define BB 32
#define NN 1024
#define FF 64
#define PP 128
#define KNN 16
#define H2 256  // 2P
#define F2 128  // 2F
#define KSEL 17
#define SVCAP 272

typedef float f32x4 __attribute__((ext_vector_type(4)));
typedef _Float16 f16x8 __attribute__((ext_vector_type(8)));
typedef _Float16 f16x4 __attribute__((ext_vector_type(4)));
typedef _Float16 f16x2 __attribute__((ext_vector_type(2)));

// ---- transcendental-free gelu: y = x * (0.5 + xc*P(xc^2)), xc = clamp(x, +-3.3)
#define GC1 0.39616247f
#define GC3 -0.05891477f
#define GC5 0.00563735f
#define GC7 -2.10439e-4f
#define GXC 3.2988f

__device__ __forceinline__ f16x8 splat8(float f) {
    _Float16 h = (_Float16)f;
    f16x8 v = {h, h, h, h, h, h, h, h};
    return v;
}
__device__ __forceinline__ f16x4 splat4(float f) {
    _Float16 h = (_Float16)f;
    f16x4 v = {h, h, h, h};
    return v;
}

// packed-f16 activation for 8 elements: gelu(g + q); v_pk_{add,mul,fma,min,max}_f16
__device__ __forceinline__ f16x8 act8(f16x8 gv, f16x8 qv) {
    const f16x8 XL = splat8(-GXC), XH = splat8(GXC);
    const f16x8 C1 = splat8(GC1), C3 = splat8(GC3), C5 = splat8(GC5), C7 = splat8(GC7);
    const f16x8 HF = splat8(0.5f);
    f16x8 x  = gv + qv;
    f16x8 xc = __builtin_elementwise_min(__builtin_elementwise_max(x, XL), XH);
    f16x8 s  = xc * xc;
    f16x8 t  = s * C7 + C5;
    t = s * t + C3;
    t = s * t + C1;
    f16x8 u = xc * t + HF;
    return x * u;
}

// packed-f16 epilogue: sum_r gelu(acc[r] + bias) over the 4 in-lane k-rows
__device__ __forceinline__ float gelu4_sum(f32x4 a, float bias) {
    f16x4 x;
    x[0] = (_Float16)(a[0] + bias);
    x[1] = (_Float16)(a[1] + bias);
    x[2] = (_Float16)(a[2] + bias);
    x[3] = (_Float16)(a[3] + bias);
    const f16x4 XL = splat4(-GXC), XH = splat4(GXC);
    const f16x4 C1 = splat4(GC1), C3 = splat4(GC3), C5 = splat4(GC5), C7 = splat4(GC7);
    const f16x4 HF = splat4(0.5f);
    f16x4 xc = __builtin_elementwise_min(__builtin_elementwise_max(x, XL), XH);
    f16x4 s  = xc * xc;
    f16x4 t  = s * C7 + C5;
    t = s * t + C3;
    t = s * t + C1;
    f16x4 u = xc * t + HF;
    f16x4 y = x * u;
    f16x2 y2 = __builtin_shufflevector(y, y, 0, 1) + __builtin_shufflevector(y, y, 2, 3);
    return (float)y2[0] + (float)y2[1];
}

// ------- prep_weights: fragment-swizzled Wcf (gq B-operand) + W2f (fused B) --------
__global__ __launch_bounds__(512) void prep_weights(const float* __restrict__ W1,
                                                    const float* __restrict__ W2,
                                                    _Float16* __restrict__ Wcf,
                                                    _Float16* __restrict__ W2f) {
    int tid = blockIdx.x * 512 + threadIdx.x;   // 0..8191
    if (tid < 4096) {
        const int lane = tid & 63, quad = lane >> 4, l16 = lane & 15;
        const int kk = (tid >> 6) & 1, n_tile = tid >> 7;
        const int n = n_tile * 16 + l16;
        const int kb = kk * 32 + quad * 8;
        f16x8 v;
#pragma unroll
        for (int j = 0; j < 8; ++j) {
            const int k = kb + j;
            float x = (n < 256) ? W1[k * 256 + n]
                                : (W1[(64 + k) * 256 + (n - 256)] - W1[k * 256 + (n - 256)]);
            v[j] = (_Float16)x;
        }
        *(f16x8*)(Wcf + (size_t)tid * 8) = v;
    } else {
        const int t2 = tid - 4096;
        const int lane = t2 & 63, quad = lane >> 4, l16 = lane & 15;
        const int nt = (t2 >> 6) & 7, kk8 = t2 >> 9;
        const int p = nt * 16 + l16;
        const int hb = kk8 * 32 + quad * 8;
        f16x8 v;
#pragma unroll
        for (int j = 0; j < 8; ++j) v[j] = (_Float16)W2[(size_t)(hb + j) * PP + p];
        *(f16x8*)(W2f + (size_t)t2 * 8) = v;
    }
}

// ------- knn_gq: blocks 0..4095 = set-based kNN; 4096..5119 = G/Q GEMM -------------
// Both paths XCD-remapped so the XCD that WRITES batch b's knn_idx/G/Q is the one
// whose fused blocks READ batch b (fused: XCD x owns batches [4x,4x+4)). This was
// worth ~11 us in R9 (rest-of-total 115.2 -> 104.2).
__global__ __launch_bounds__(512, 8) void knn_gq(const float* __restrict__ points,
                                                 int* __restrict__ idx_out,
                                                 const float* __restrict__ feat,
                                                 const _Float16* __restrict__ Wcf,
                                                 const float* __restrict__ b1,
                                                 _Float16* __restrict__ Gall,
                                                 _Float16* __restrict__ Qall) {
    // one LDS arena, aliased per path (kNN: 35840 B, gq: 34816 B)
    __shared__ __align__(16) unsigned char smem[35840];
    const int t = threadIdx.x;

    if (blockIdx.x >= 4096) {
        // ---------------- gq path: 32 rows/block, 8 waves (two 16-row subtiles) ----
        _Float16 (*st)[16][136] = (_Float16(*)[16][136])smem;
        const int w8 = t >> 6, lane = t & 63;
        const int w4 = w8 & 3;                       // role within subtile
        const int quad = lane >> 4, l16 = lane & 15;
        const int gb = blockIdx.x - 4096;            // 0..1023; XCD = gb % 8
        const int gbl = ((gb & 7) << 7) | (gb >> 3); // XCD x -> rows of batches [4x,4x+4)
        const int m0 = gbl * 32 + (w8 >> 2) * 16;

        f16x8 a[2];
#pragma unroll
        for (int kk = 0; kk < 2; ++kk) {
            const float* ap = feat + (size_t)(m0 + l16) * 64 + kk * 32 + quad * 8;
            float4 a0 = *(const float4*)ap, a1 = *(const float4*)(ap + 4);
            f16x8 v;
            v[0] = (_Float16)a0.x; v[1] = (_Float16)a0.y; v[2] = (_Float16)a0.z; v[3] = (_Float16)a0.w;
            v[4] = (_Float16)a1.x; v[5] = (_Float16)a1.y; v[6] = (_Float16)a1.z; v[7] = (_Float16)a1.w;
            a[kk] = v;
        }
        f32x4 acc[8];
#pragma unroll
        for (int nt = 0; nt < 8; ++nt) acc[nt] = (f32x4){0.f, 0.f, 0.f, 0.f};
#pragma unroll
        for (int kk = 0; kk < 2; ++kk)
#pragma unroll
            for (int nt = 0; nt < 8; ++nt) {
                f16x8 bf = *(const f16x8*)(Wcf + (size_t)(((w4 * 8 + nt) * 2 + kk) * 64 + lane) * 8);
                acc[nt] = __builtin_amdgcn_mfma_f32_16x16x32_f16(a[kk], bf, acc[nt], 0, 0, 0);
            }

        const bool isQ = (w4 >= 2);
#pragma unroll
        for (int nt = 0; nt < 8; ++nt) {
            const int col = nt * 16 + l16;
            const float bias = isQ ? b1[(w4 - 2) * 128 + col] : 0.f;
#pragma unroll
            for (int r = 0; r < 4; ++r)
                st[w8][quad * 4 + r][col] = (_Float16)(acc[nt][r] + bias);
        }
        __syncthreads();

        const int row = lane >> 2, c = lane & 3;
        const int m = m0 + row;
#pragma unroll
        for (int i = 0; i < 4; ++i) {
            const int col = c * 32 + i * 8;
            f16x8 v = *(const f16x8*)&st[w8][row][col];
            if (!isQ) *(f16x8*)(Gall + (size_t)m * H2 + w4 * 128 + col) = v;
            else      *(f16x8*)(Qall + (size_t)m * H2 + (w4 - 2) * 128 + col) = v;
        }
        return;
    }

    // ---------------- kNN path ----------------
    float2* pxy = (float2*)smem;                                // 8 KB
    float2* pzr = (float2*)(smem + 8192);                       // 8 KB
    unsigned (*sv_val)[SVCAP] = (unsigned(*)[SVCAP])(smem + 16384);   // 8704 B
    unsigned (*sv_idx)[SVCAP] = (unsigned(*)[SVCAP])(smem + 25088);   // 8704 B
    unsigned (*tie_idx)[64]   = (unsigned(*)[64])(smem + 33792);      // 2048 B

    // XCD-align with fused: physical p (XCD p%8) -> logical lb so batch lb>>7 in [4x,4x+4)
    const int lbk = ((blockIdx.x & 7) << 9) | (blockIdx.x >> 3);

    const int w = t >> 6, lane = t & 63;
    const int b = lbk >> 7;
    const int q0 = (lbk & 127) * 8;
    const float* pb = points + (size_t)b * NN * 3;
    const unsigned long long lt = (1ull << lane) - 1ull;

    for (int i = t; i < NN; i += 512) {
        float x = pb[3 * i], y = pb[3 * i + 1], z = pb[3 * i + 2];
        float r = __fadd_rn(__fadd_rn(__fmul_rn(x, x), __fmul_rn(y, y)), __fmul_rn(z, z));
        pxy[i] = make_float2(x, y);
        pzr[i] = make_float2(z, r);
    }
    __syncthreads();

    const int qn = q0 + w;
    const int gq = b * NN + qn;
    const float2 qv1 = pxy[qn], qv2 = pzr[qn];
    const float qx = qv1.x, qy = qv1.y, qz = qv2.x, qw = qv2.y;

    float D[16];
#pragma unroll
    for (int j = 0; j < 16; ++j) {
        const int m = j * 64 + lane;
        const float2 v1 = pxy[m], v2 = pzr[m];
        float dot = __fadd_rn(__fadd_rn(__fmul_rn(qx, v1.x), __fmul_rn(qy, v1.y)),
                              __fmul_rn(qz, v2.x));
        D[j] = __fadd_rn(__fadd_rn(__fsub_rn(qw, __fmul_rn(2.0f, dot)), v2.y), 1e-5f);
    }

    float mnf = D[0];
#pragma unroll
    for (int j = 1; j < 16; ++j) mnf = fminf(mnf, D[j]);
    const unsigned mbits = __float_as_uint(mnf);

    // T_ub via 16-round radix on the HIGH 16 bits of the lane-mins.
    const unsigned mhi = mbits >> 16;
    unsigned Thi = 0;
#pragma unroll
    for (int bit = 15; bit >= 0; --bit) {
        unsigned cand = Thi | (1u << bit);
        int cnt = __popcll(__ballot(mhi < cand));
        if (cnt < KSEL) Thi = cand;
    }
    const unsigned T = (Thi << 16) | 0xFFFFu;

    unsigned base = 0;
#pragma unroll
    for (int j = 0; j < 16; ++j) {
        unsigned vb = __float_as_uint(D[j]);
        bool keep = (vb <= T);
        unsigned long long m = __ballot(keep);
        if (keep) {
            unsigned pos = base + (unsigned)__popcll(m & lt);
            if (pos < SVCAP) { sv_val[w][pos] = vb; sv_idx[w][pos] = j * 64 + lane; }
        }
        base += (unsigned)__popcll(m);
    }
    unsigned C = base > SVCAP ? SVCAP : base;

    // register-cache survivors (<=5 slots/lane); later loops are register-only.
    unsigned rv[5], ri[5];
#pragma unroll
    for (int s = 0; s < 5; ++s) {
        int i = s * 64 + lane;
        bool ok = (i < (int)C);
        rv[s] = ok ? sv_val[w][i] : 0xFFFFFFFFu;
        ri[s] = ok ? sv_idx[w][i] : 0xFFFFFFFFu;
    }

    unsigned Ts = 0;
    if (C <= 64) {
#pragma unroll
        for (int bit = 31; bit >= 0; --bit) {
            unsigned cand = Ts | (1u << bit);
            int cnt = __popcll(__ballot(rv[0] < cand));
            if (cnt < KSEL) Ts = cand;
        }
    } else {
#pragma unroll
        for (int bit = 31; bit >= 0; --bit) {
            unsigned cand = Ts | (1u << bit);
            int cnt = 0;
#pragma unroll
            for (int s = 0; s < 5; ++s)
                cnt += __popcll(__ballot(rv[s] < cand));
            if (cnt < KSEL) Ts = cand;
        }
    }

    int L = 0;
#pragma unroll
    for (int s = 0; s < 5; ++s) L += __popcll(__ballot(rv[s] < Ts));
    const int need = KSEL - L;

    unsigned vmin_l = 0xFFFFFFFFu;
#pragma unroll
    for (int s = 0; s < 5; ++s) vmin_l = vmin_l < rv[s] ? vmin_l : rv[s];
#pragma unroll
    for (int off = 32; off >= 1; off >>= 1) {
        unsigned o2 = __shfl_xor(vmin_l, off, 64);
        vmin_l = vmin_l < o2 ? vmin_l : o2;
    }
    const unsigned Vmin = vmin_l;
    unsigned imin_l = 0xFFFFFFFFu;
#pragma unroll
    for (int s = 0; s < 5; ++s)
        if (rv[s] == Vmin && ri[s] < imin_l) imin_l = ri[s];
#pragma unroll
    for (int off = 32; off >= 1; off >>= 1) {
        unsigned o2 = __shfl_xor(imin_l, off, 64);
        imin_l = imin_l < o2 ? imin_l : o2;
    }
    const unsigned dropIdx = imin_l;

    int* o = idx_out + (size_t)gq * KNN;
    unsigned wbase = 0, tbase = 0;
#pragma unroll
    for (int s = 0; s < 5; ++s) {
        unsigned vb = rv[s], mi = ri[s];
        bool wk = (vb < Ts) && (mi != dropIdx);
        unsigned long long wm = __ballot(wk);
        if (wk) o[wbase + (unsigned)__popcll(wm & lt)] = (int)mi;
        wbase += (unsigned)__popcll(wm);
        bool tk = (vb == Ts);
        unsigned long long tm2 = __ballot(tk);
        if (tk) {
            unsigned tp = tbase + (unsigned)__popcll(tm2 & lt);
            if (tp < 64) tie_idx[w][tp] = mi;
        }
        tbase += (unsigned)__popcll(tm2);
    }
    unsigned tc = tbase > 64 ? 64 : tbase;
    if ((int)tc == need) {
        bool tk = (lane < (int)tc);
        unsigned mi2 = tk ? tie_idx[w][lane] : 0xFFFFFFFFu;
        tk = tk && (mi2 != dropIdx);
        unsigned long long m3 = __ballot(tk);
        if (tk) o[wbase + (unsigned)__popcll(m3 & lt)] = (int)mi2;
    } else if (lane == 0) {
        unsigned pos = wbase;
        for (int r = 0; r < need; ++r) {
            unsigned best = 0xFFFFFFFFu; int bj = 0;
            for (int j2 = 0; j2 < (int)tc; ++j2) {
                unsigned mi = tie_idx[w][j2];
                if (mi < best) { best = mi; bj = j2; }
            }
            tie_idx[w][bj] = 0xFFFFFFFFu;
            if (best != dropIdx) o[pos++] = (int)best;
        }
    }
}

// ---------------- fused_mlp16: out = mean_k gelu(gelu(G[idx]+Q) @ W2 + b2) ----------
// VERBATIM mlp12 structure — the measured 73.5 us champion. R7 (named-register
// prefetch), R8 (asm vmcnt pipeline), R9 (prologue hoist + setprio) all regressed:
// the compiler's own schedule of the plain form wins. Do not re-add pipelining
// at source level.
__global__ __launch_bounds__(512, 3) void fused_mlp16(const _Float16* __restrict__ Gall,
                                                      const _Float16* __restrict__ Qall,
                                                      const int* __restrict__ knn_idx,
                                                      const _Float16* __restrict__ W2f,
                                                      const float* __restrict__ b2,
                                                      float* __restrict__ out) {
    __shared__ __align__(16) _Float16 w2s[32768];   // 64 KB: ALL of W2f
    const int t = threadIdx.x, w = t >> 6, lane = t & 63;
    const int quad = lane >> 4, l16 = lane & 15;

    // XCD-aware swizzle: 2048 blocks, XCD x owns logical [256x, 256x+256) = 4 batches.
    const int lb = ((blockIdx.x & 7) << 8) | (blockIdx.x >> 3);

    const int q0 = lb * 16 + w * 2;               // queries q0, q0+1; block covers 16
    const int b = q0 >> 10;
    const int nb0 = knn_idx[q0 * KNN + l16];
    const int nb1 = knn_idx[(q0 + 1) * KNN + l16];
    const _Float16* g0 = Gall + ((size_t)(b << 10) + nb0) * H2;
    const _Float16* g1 = Gall + ((size_t)(b << 10) + nb1) * H2;
    const _Float16* qq0 = Qall + (size_t)q0 * H2;
    const _Float16* qq1 = qq0 + H2;

    // stage entire W2f: 8 x f16x8 per thread
#pragma unroll
    for (int i = 0; i < 8; ++i) {
        f16x8 v = *(const f16x8*)(W2f + (size_t)(i * 4096 + t * 8));
        *(f16x8*)&w2s[i * 4096 + t * 8] = v;
    }

    f32x4 acc[2][8];
#pragma unroll
    for (int tm = 0; tm < 2; ++tm)
#pragma unroll
        for (int nt = 0; nt < 8; ++nt) acc[tm][nt] = (f32x4){0.f, 0.f, 0.f, 0.f};

    __syncthreads();

    // single barrier-free compute region: 8 K-slices of 32
#pragma unroll
    for (int rk = 0; rk < 8; ++rk) {
        const int ho = rk * 32 + quad * 8;
        f16x8 gA = *(const f16x8*)(g0 + ho);
        f16x8 qA = *(const f16x8*)(qq0 + ho);
        f16x8 gB = *(const f16x8*)(g1 + ho);
        f16x8 qB = *(const f16x8*)(qq1 + ho);
        f16x8 a0 = act8(gA, qA);
        f16x8 a1 = act8(gB, qB);
        const _Float16* bb = &w2s[rk * 4096 + lane * 8];
#pragma unroll
        for (int nt = 0; nt < 8; ++nt) {
            f16x8 bf = *(const f16x8*)(bb + nt * 512);
            acc[0][nt] = __builtin_amdgcn_mfma_f32_16x16x32_f16(a0, bf, acc[0][nt], 0, 0, 0);
            acc[1][nt] = __builtin_amdgcn_mfma_f32_16x16x32_f16(a1, bf, acc[1][nt], 0, 0, 0);
        }
    }

    // Epilogue: w2s no longer needed -> alias obuf into it (after a barrier).
    __syncthreads();
    float* obuf = (float*)w2s;       // 8 KB used of 64 KB
#pragma unroll
    for (int tm = 0; tm < 2; ++tm)
#pragma unroll
        for (int nt = 0; nt < 8; ++nt) {
            const float bias = b2[nt * 16 + l16];
            float s = gelu4_sum(acc[tm][nt], bias);
            s += __shfl_xor(s, 16, 64);
            s += __shfl_xor(s, 32, 64);
            if (quad == 0)
                obuf[(w * 2 + tm) * 128 + nt * 16 + l16] = s * 0.0625f;
        }
    __syncthreads();
    {
        // block covers queries [lb*16, lb*16+16) -> 8 KB contiguous in out
        float4 v = *(const float4*)&obuf[t * 4];
        *(float4*)(out + (size_t)lb * 2048 + t * 4) = v;
    }
}

extern "C" void kernel_launch(void* const* d_in, const int* in_sizes, int n_in,
                              void* d_out, int out_size, void* d_ws, size_t ws_size,
                              hipStream_t stream) {
    const float* points   = (const float*)d_in[0];
    const float* features = (const float*)d_in[1];
    const float* W1 = (const float*)d_in[2];
    const float* b1 = (const float*)d_in[3];
    const float* W2 = (const float*)d_in[4];
    const float* b2 = (const float*)d_in[5];
    float* out = (float*)d_out;

    const size_t IDX_B  = (size_t)BB * NN * KNN * 4;   // 2 MB
    const size_t WCF_B  = 512 * 64 * 2;                // 64 KB
    const size_t W2F_B  = 256 * 128 * 2;               // 64 KB
    const size_t G_B    = (size_t)BB * NN * H2 * 2;    // 16 MB

    int* knn_idx = (int*)d_ws;
    char* p = (char*)d_ws + IDX_B;
    _Float16* Wcf  = (_Float16*)p;  p += WCF_B;
    _Float16* W2f  = (_Float16*)p;  p += W2F_B;
    _Float16* Gall = (_Float16*)p;  p += G_B;
    _Float16* Qall = (_Float16*)p;                     // 16 MB -> total ~34.1 MB

    prep_weights<<<16, 512, 0, stream>>>(W1, W2, Wcf, W2f);
    knn_gq<<<5120, 512, 0, stream>>>(points, knn_idx, features, Wcf, b1, Gall, Qall);
    fused_mlp16<<<2048, 512, 0, stream>>>(Gall, Qall, knn_idx, W2f, b2, out);
}

// Round 11
// 184.490 us; speedup vs baseline: 1.0201x; 1.0201x over previous
//
#include <hip/hip_runtime.h>
#include <math.h>

#define BB 32
#define NN 1024
#define FF 64
#define PP 128
#define KNN 16
#define H2 256  // 2P
#define F2 128  // 2F
#define KSEL 17
#define SVCAP 272

typedef float f32x4 __attribute__((ext_vector_type(4)));
typedef _Float16 f16x8 __attribute__((ext_vector_type(8)));
typedef _Float16 f16x4 __attribute__((ext_vector_type(4)));
typedef _Float16 f16x2 __attribute__((ext_vector_type(2)));

// ---- transcendental-free gelu: y = x * (0.5 + xc*P(xc^2)), xc = clamp(x, +-3.3)
#define GC1 0.39616247f
#define GC3 -0.05891477f
#define GC5 0.00563735f
#define GC7 -2.10439e-4f
#define GXC 3.2988f

__device__ __forceinline__ f16x8 splat8(float f) {
    _Float16 h = (_Float16)f;
    f16x8 v = {h, h, h, h, h, h, h, h};
    return v;
}
__device__ __forceinline__ f16x4 splat4(float f) {
    _Float16 h = (_Float16)f;
    f16x4 v = {h, h, h, h};
    return v;
}

// packed-f16 activation for 8 elements: gelu(g + q); v_pk_{add,mul,fma,min,max}_f16
__device__ __forceinline__ f16x8 act8(f16x8 gv, f16x8 qv) {
    const f16x8 XL = splat8(-GXC), XH = splat8(GXC);
    const f16x8 C1 = splat8(GC1), C3 = splat8(GC3), C5 = splat8(GC5), C7 = splat8(GC7);
    const f16x8 HF = splat8(0.5f);
    f16x8 x  = gv + qv;
    f16x8 xc = __builtin_elementwise_min(__builtin_elementwise_max(x, XL), XH);
    f16x8 s  = xc * xc;
    f16x8 t  = s * C7 + C5;
    t = s * t + C3;
    t = s * t + C1;
    f16x8 u = xc * t + HF;
    return x * u;
}

// packed-f16 epilogue: sum_r gelu(acc[r] + bias) over the 4 in-lane k-rows
__device__ __forceinline__ float gelu4_sum(f32x4 a, float bias) {
    f16x4 x;
    x[0] = (_Float16)(a[0] + bias);
    x[1] = (_Float16)(a[1] + bias);
    x[2] = (_Float16)(a[2] + bias);
    x[3] = (_Float16)(a[3] + bias);
    const f16x4 XL = splat4(-GXC), XH = splat4(GXC);
    const f16x4 C1 = splat4(GC1), C3 = splat4(GC3), C5 = splat4(GC5), C7 = splat4(GC7);
    const f16x4 HF = splat4(0.5f);
    f16x4 xc = __builtin_elementwise_min(__builtin_elementwise_max(x, XL), XH);
    f16x4 s  = xc * xc;
    f16x4 t  = s * C7 + C5;
    t = s * t + C3;
    t = s * t + C1;
    f16x4 u = xc * t + HF;
    f16x4 y = x * u;
    f16x2 y2 = __builtin_shufflevector(y, y, 0, 1) + __builtin_shufflevector(y, y, 2, 3);
    return (float)y2[0] + (float)y2[1];
}

// async global->LDS, 16B/lane: per-lane GLOBAL address, wave-uniform LDS base + lane*16.
// The LDS write is a side effect the compiler cannot roll back to the use site --
// this is the prefetch mechanism that survives register-pressure heuristics.
__device__ __forceinline__ void gld16(const void* g, void* l) {
    __builtin_amdgcn_global_load_lds((const __attribute__((address_space(1))) unsigned int*)g,
                                     (__attribute__((address_space(3))) unsigned int*)l,
                                     16, 0, 0);
}

// ------- prep_weights: fragment-swizzled Wcf (gq B-operand) + W2f (fused B) --------
__global__ __launch_bounds__(512) void prep_weights(const float* __restrict__ W1,
                                                    const float* __restrict__ W2,
                                                    _Float16* __restrict__ Wcf,
                                                    _Float16* __restrict__ W2f) {
    int tid = blockIdx.x * 512 + threadIdx.x;   // 0..8191
    if (tid < 4096) {
        const int lane = tid & 63, quad = lane >> 4, l16 = lane & 15;
        const int kk = (tid >> 6) & 1, n_tile = tid >> 7;
        const int n = n_tile * 16 + l16;
        const int kb = kk * 32 + quad * 8;
        f16x8 v;
#pragma unroll
        for (int j = 0; j < 8; ++j) {
            const int k = kb + j;
            float x = (n < 256) ? W1[k * 256 + n]
                                : (W1[(64 + k) * 256 + (n - 256)] - W1[k * 256 + (n - 256)]);
            v[j] = (_Float16)x;
        }
        *(f16x8*)(Wcf + (size_t)tid * 8) = v;
    } else {
        const int t2 = tid - 4096;
        const int lane = t2 & 63, quad = lane >> 4, l16 = lane & 15;
        const int nt = (t2 >> 6) & 7, kk8 = t2 >> 9;
        const int p = nt * 16 + l16;
        const int hb = kk8 * 32 + quad * 8;
        f16x8 v;
#pragma unroll
        for (int j = 0; j < 8; ++j) v[j] = (_Float16)W2[(size_t)(hb + j) * PP + p];
        *(f16x8*)(W2f + (size_t)t2 * 8) = v;
    }
}

// ------- knn_gq: blocks 0..4095 = set-based kNN; 4096..5119 = G/Q GEMM -------------
// (verbatim R9/R10 version: XCD writer/reader alignment + register-cached survivors)
__global__ __launch_bounds__(512, 8) void knn_gq(const float* __restrict__ points,
                                                 int* __restrict__ idx_out,
                                                 const float* __restrict__ feat,
                                                 const _Float16* __restrict__ Wcf,
                                                 const float* __restrict__ b1,
                                                 _Float16* __restrict__ Gall,
                                                 _Float16* __restrict__ Qall) {
    __shared__ __align__(16) unsigned char smem[35840];
    const int t = threadIdx.x;

    if (blockIdx.x >= 4096) {
        _Float16 (*st)[16][136] = (_Float16(*)[16][136])smem;
        const int w8 = t >> 6, lane = t & 63;
        const int w4 = w8 & 3;
        const int quad = lane >> 4, l16 = lane & 15;
        const int gb = blockIdx.x - 4096;
        const int gbl = ((gb & 7) << 7) | (gb >> 3);
        const int m0 = gbl * 32 + (w8 >> 2) * 16;

        f16x8 a[2];
#pragma unroll
        for (int kk = 0; kk < 2; ++kk) {
            const float* ap = feat + (size_t)(m0 + l16) * 64 + kk * 32 + quad * 8;
            float4 a0 = *(const float4*)ap, a1 = *(const float4*)(ap + 4);
            f16x8 v;
            v[0] = (_Float16)a0.x; v[1] = (_Float16)a0.y; v[2] = (_Float16)a0.z; v[3] = (_Float16)a0.w;
            v[4] = (_Float16)a1.x; v[5] = (_Float16)a1.y; v[6] = (_Float16)a1.z; v[7] = (_Float16)a1.w;
            a[kk] = v;
        }
        f32x4 acc[8];
#pragma unroll
        for (int nt = 0; nt < 8; ++nt) acc[nt] = (f32x4){0.f, 0.f, 0.f, 0.f};
#pragma unroll
        for (int kk = 0; kk < 2; ++kk)
#pragma unroll
            for (int nt = 0; nt < 8; ++nt) {
                f16x8 bf = *(const f16x8*)(Wcf + (size_t)(((w4 * 8 + nt) * 2 + kk) * 64 + lane) * 8);
                acc[nt] = __builtin_amdgcn_mfma_f32_16x16x32_f16(a[kk], bf, acc[nt], 0, 0, 0);
            }

        const bool isQ = (w4 >= 2);
#pragma unroll
        for (int nt = 0; nt < 8; ++nt) {
            const int col = nt * 16 + l16;
            const float bias = isQ ? b1[(w4 - 2) * 128 + col] : 0.f;
#pragma unroll
            for (int r = 0; r < 4; ++r)
                st[w8][quad * 4 + r][col] = (_Float16)(acc[nt][r] + bias);
        }
        __syncthreads();

        const int row = lane >> 2, c = lane & 3;
        const int m = m0 + row;
#pragma unroll
        for (int i = 0; i < 4; ++i) {
            const int col = c * 32 + i * 8;
            f16x8 v = *(const f16x8*)&st[w8][row][col];
            if (!isQ) *(f16x8*)(Gall + (size_t)m * H2 + w4 * 128 + col) = v;
            else      *(f16x8*)(Qall + (size_t)m * H2 + (w4 - 2) * 128 + col) = v;
        }
        return;
    }

    float2* pxy = (float2*)smem;
    float2* pzr = (float2*)(smem + 8192);
    unsigned (*sv_val)[SVCAP] = (unsigned(*)[SVCAP])(smem + 16384);
    unsigned (*sv_idx)[SVCAP] = (unsigned(*)[SVCAP])(smem + 25088);
    unsigned (*tie_idx)[64]   = (unsigned(*)[64])(smem + 33792);

    const int lbk = ((blockIdx.x & 7) << 9) | (blockIdx.x >> 3);

    const int w = t >> 6, lane = t & 63;
    const int b = lbk >> 7;
    const int q0 = (lbk & 127) * 8;
    const float* pb = points + (size_t)b * NN * 3;
    const unsigned long long lt = (1ull << lane) - 1ull;

    for (int i = t; i < NN; i += 512) {
        float x = pb[3 * i], y = pb[3 * i + 1], z = pb[3 * i + 2];
        float r = __fadd_rn(__fadd_rn(__fmul_rn(x, x), __fmul_rn(y, y)), __fmul_rn(z, z));
        pxy[i] = make_float2(x, y);
        pzr[i] = make_float2(z, r);
    }
    __syncthreads();

    const int qn = q0 + w;
    const int gq = b * NN + qn;
    const float2 qv1 = pxy[qn], qv2 = pzr[qn];
    const float qx = qv1.x, qy = qv1.y, qz = qv2.x, qw = qv2.y;

    float D[16];
#pragma unroll
    for (int j = 0; j < 16; ++j) {
        const int m = j * 64 + lane;
        const float2 v1 = pxy[m], v2 = pzr[m];
        float dot = __fadd_rn(__fadd_rn(__fmul_rn(qx, v1.x), __fmul_rn(qy, v1.y)),
                              __fmul_rn(qz, v2.x));
        D[j] = __fadd_rn(__fadd_rn(__fsub_rn(qw, __fmul_rn(2.0f, dot)), v2.y), 1e-5f);
    }

    float mnf = D[0];
#pragma unroll
    for (int j = 1; j < 16; ++j) mnf = fminf(mnf, D[j]);
    const unsigned mbits = __float_as_uint(mnf);

    const unsigned mhi = mbits >> 16;
    unsigned Thi = 0;
#pragma unroll
    for (int bit = 15; bit >= 0; --bit) {
        unsigned cand = Thi | (1u << bit);
        int cnt = __popcll(__ballot(mhi < cand));
        if (cnt < KSEL) Thi = cand;
    }
    const unsigned T = (Thi << 16) | 0xFFFFu;

    unsigned base = 0;
#pragma unroll
    for (int j = 0; j < 16; ++j) {
        unsigned vb = __float_as_uint(D[j]);
        bool keep = (vb <= T);
        unsigned long long m = __ballot(keep);
        if (keep) {
            unsigned pos = base + (unsigned)__popcll(m & lt);
            if (pos < SVCAP) { sv_val[w][pos] = vb; sv_idx[w][pos] = j * 64 + lane; }
        }
        base += (unsigned)__popcll(m);
    }
    unsigned C = base > SVCAP ? SVCAP : base;

    unsigned rv[5], ri[5];
#pragma unroll
    for (int s = 0; s < 5; ++s) {
        int i = s * 64 + lane;
        bool ok = (i < (int)C);
        rv[s] = ok ? sv_val[w][i] : 0xFFFFFFFFu;
        ri[s] = ok ? sv_idx[w][i] : 0xFFFFFFFFu;
    }

    unsigned Ts = 0;
    if (C <= 64) {
#pragma unroll
        for (int bit = 31; bit >= 0; --bit) {
            unsigned cand = Ts | (1u << bit);
            int cnt = __popcll(__ballot(rv[0] < cand));
            if (cnt < KSEL) Ts = cand;
        }
    } else {
#pragma unroll
        for (int bit = 31; bit >= 0; --bit) {
            unsigned cand = Ts | (1u << bit);
            int cnt = 0;
#pragma unroll
            for (int s = 0; s < 5; ++s)
                cnt += __popcll(__ballot(rv[s] < cand));
            if (cnt < KSEL) Ts = cand;
        }
    }

    int L = 0;
#pragma unroll
    for (int s = 0; s < 5; ++s) L += __popcll(__ballot(rv[s] < Ts));
    const int need = KSEL - L;

    unsigned vmin_l = 0xFFFFFFFFu;
#pragma unroll
    for (int s = 0; s < 5; ++s) vmin_l = vmin_l < rv[s] ? vmin_l : rv[s];
#pragma unroll
    for (int off = 32; off >= 1; off >>= 1) {
        unsigned o2 = __shfl_xor(vmin_l, off, 64);
        vmin_l = vmin_l < o2 ? vmin_l : o2;
    }
    const unsigned Vmin = vmin_l;
    unsigned imin_l = 0xFFFFFFFFu;
#pragma unroll
    for (int s = 0; s < 5; ++s)
        if (rv[s] == Vmin && ri[s] < imin_l) imin_l = ri[s];
#pragma unroll
    for (int off = 32; off >= 1; off >>= 1) {
        unsigned o2 = __shfl_xor(imin_l, off, 64);
        imin_l = imin_l < o2 ? imin_l : o2;
    }
    const unsigned dropIdx = imin_l;

    int* o = idx_out + (size_t)gq * KNN;
    unsigned wbase = 0, tbase = 0;
#pragma unroll
    for (int s = 0; s < 5; ++s) {
        unsigned vb = rv[s], mi = ri[s];
        bool wk = (vb < Ts) && (mi != dropIdx);
        unsigned long long wm = __ballot(wk);
        if (wk) o[wbase + (unsigned)__popcll(wm & lt)] = (int)mi;
        wbase += (unsigned)__popcll(wm);
        bool tk = (vb == Ts);
        unsigned long long tm2 = __ballot(tk);
        if (tk) {
            unsigned tp = tbase + (unsigned)__popcll(tm2 & lt);
            if (tp < 64) tie_idx[w][tp] = mi;
        }
        tbase += (unsigned)__popcll(tm2);
    }
    unsigned tc = tbase > 64 ? 64 : tbase;
    if ((int)tc == need) {
        bool tk = (lane < (int)tc);
        unsigned mi2 = tk ? tie_idx[w][lane] : 0xFFFFFFFFu;
        tk = tk && (mi2 != dropIdx);
        unsigned long long m3 = __ballot(tk);
        if (tk) o[wbase + (unsigned)__popcll(m3 & lt)] = (int)mi2;
    } else if (lane == 0) {
        unsigned pos = wbase;
        for (int r = 0; r < need; ++r) {
            unsigned best = 0xFFFFFFFFu; int bj = 0;
            for (int j2 = 0; j2 < (int)tc; ++j2) {
                unsigned mi = tie_idx[w][j2];
                if (mi < best) { best = mi; bj = j2; }
            }
            tie_idx[w][bj] = 0xFFFFFFFFu;
            if (best != dropIdx) o[pos++] = (int)best;
        }
    }
}

// ---------------- fused_mlp17: out = mean_k gelu(gelu(G[idx]+Q) @ W2 + b2) ----------
// R6/R7/R9: VGPR-prefetch rolled back by regalloc; R8: asm+sched_barrier killed the
// schedule. This version prefetches the G gathers into per-wave LDS slots via
// global_load_lds (an LDS write is a side effect the compiler CANNOT roll back),
// double-buffered 2 rk ahead, with ONE counted vmcnt per rk and NO sched_barrier
// (MFMAs stay free to move; consumers are ds_reads, ordered by the memory clobber).
// Q is staged once per wave; W2f in two 32 KB halves. LDS 72 KB -> still 2 blk/CU.
// vmcnt math: exactly 2 loads issued per rk (after the slot is consumed);
// wait vmcnt(2) rk0-6, vmcnt(0) rk7; barriers drain everything in between.
__global__ __launch_bounds__(512, 3) void fused_mlp17(const _Float16* __restrict__ Gall,
                                                      const _Float16* __restrict__ Qall,
                                                      const int* __restrict__ knn_idx,
                                                      const _Float16* __restrict__ W2f,
                                                      const float* __restrict__ b2,
                                                      float* __restrict__ out) {
    __shared__ __align__(16) _Float16 w2s[16384];        // 32 KB: half of W2f
    __shared__ __align__(16) _Float16 gbuf[8][2][1024];  // 32 KB: per-wave G dbuf
    __shared__ __align__(16) _Float16 qbuf[8][512];      //  8 KB: per-wave Q rows
    const int t = threadIdx.x, w = t >> 6, lane = t & 63;
    const int quad = lane >> 4, l16 = lane & 15;

    const int lb = ((blockIdx.x & 7) << 8) | (blockIdx.x >> 3);

    const int q0 = lb * 16 + w * 2;
    const int b = q0 >> 10;
    const int nb0 = knn_idx[q0 * KNN + l16];
    const int nb1 = knn_idx[(q0 + 1) * KNN + l16];
    const _Float16* g0 = Gall + ((size_t)(b << 10) + nb0) * H2;
    const _Float16* g1 = Gall + ((size_t)(b << 10) + nb1) * H2;

    // per-lane byte addresses
    const char* aG0 = (const char*)g0 + quad * 16;
    const char* aG1 = (const char*)g1 + quad * 16;
    const char* aQ  = (const char*)(Qall + (size_t)q0 * H2) + (lane >> 5) * (H2 * 2) + (lane & 31) * 16;
    const char* w2b = (const char*)W2f;

    // ---- prologue: stage Q (1 instr), W2f half0 (4), G pairs rk0/rk1 (4) ----
    gld16(aQ, &qbuf[w][0]);
#pragma unroll
    for (int i = 0; i < 4; ++i)
        gld16(w2b + i * 8192 + w * 1024 + lane * 16, &w2s[i * 4096 + w * 512]);
    gld16(aG0,      &gbuf[w][0][0]);
    gld16(aG1,      &gbuf[w][0][512]);
    gld16(aG0 + 64, &gbuf[w][1][0]);
    gld16(aG1 + 64, &gbuf[w][1][512]);

    f32x4 acc[2][8];
#pragma unroll
    for (int tm = 0; tm < 2; ++tm)
#pragma unroll
        for (int nt = 0; nt < 8; ++nt) acc[tm][nt] = (f32x4){0.f, 0.f, 0.f, 0.f};

    __syncthreads();   // drains all prologue loads (vmcnt(0) implied)

#define STEP(RK, WN)                                                                   \
    {                                                                                  \
        asm volatile("s_waitcnt vmcnt(%c0)" ::"i"(WN) : "memory");                     \
        f16x8 gA = *(const f16x8*)&gbuf[w][(RK) & 1][lane * 8];                        \
        f16x8 gB = *(const f16x8*)&gbuf[w][(RK) & 1][512 + lane * 8];                  \
        f16x8 qA = *(const f16x8*)&qbuf[w][(RK) * 32 + quad * 8];                      \
        f16x8 qB = *(const f16x8*)&qbuf[w][256 + (RK) * 32 + quad * 8];                \
        f16x8 a0 = act8(gA, qA);                                                       \
        f16x8 a1 = act8(gB, qB);                                                       \
        if ((RK) < 6) {                                                                \
            gld16(aG0 + ((RK) + 2) * 64, &gbuf[w][(RK) & 1][0]);                       \
            gld16(aG1 + ((RK) + 2) * 64, &gbuf[w][(RK) & 1][512]);                     \
        }                                                                              \
        const _Float16* bb = &w2s[((RK) & 3) * 4096 + lane * 8];                       \
        _Pragma("unroll")                                                              \
        for (int nt = 0; nt < 8; ++nt) {                                               \
            f16x8 bf = *(const f16x8*)(bb + nt * 512);                                 \
            acc[0][nt] = __builtin_amdgcn_mfma_f32_16x16x32_f16(a0, bf, acc[0][nt], 0, 0, 0); \
            acc[1][nt] = __builtin_amdgcn_mfma_f32_16x16x32_f16(a1, bf, acc[1][nt], 0, 0, 0); \
        }                                                                              \
    }

    STEP(0, 2) STEP(1, 2) STEP(2, 2) STEP(3, 2)

    // ---- mid-phase: swap in W2f half1 (barriers drain in-flight prefetches) ----
    __syncthreads();
#pragma unroll
    for (int i = 0; i < 4; ++i)
        gld16(w2b + 32768 + i * 8192 + w * 1024 + lane * 16, &w2s[i * 4096 + w * 512]);
    __syncthreads();

    STEP(4, 2) STEP(5, 2) STEP(6, 2) STEP(7, 0)
#undef STEP

    // Epilogue: w2s no longer needed -> alias obuf into it (after a barrier).
    __syncthreads();
    float* obuf = (float*)w2s;       // 8 KB used of 32 KB
#pragma unroll
    for (int tm = 0; tm < 2; ++tm)
#pragma unroll
        for (int nt = 0; nt < 8; ++nt) {
            const float bias = b2[nt * 16 + l16];
            float s = gelu4_sum(acc[tm][nt], bias);
            s += __shfl_xor(s, 16, 64);
            s += __shfl_xor(s, 32, 64);
            if (quad == 0)
                obuf[(w * 2 + tm) * 128 + nt * 16 + l16] = s * 0.0625f;
        }
    __syncthreads();
    {
        float4 v = *(const float4*)&obuf[t * 4];
        *(float4*)(out + (size_t)lb * 2048 + t * 4) = v;
    }
}

extern "C" void kernel_launch(void* const* d_in, const int* in_sizes, int n_in,
                              void* d_out, int out_size, void* d_ws, size_t ws_size,
                              hipStream_t stream) {
    const float* points   = (const float*)d_in[0];
    const float* features = (const float*)d_in[1];
    const float* W1 = (const float*)d_in[2];
    const float* b1 = (const float*)d_in[3];
    const float* W2 = (const float*)d_in[4];
    const float* b2 = (const float*)d_in[5];
    float* out = (float*)d_out;

    const size_t IDX_B  = (size_t)BB * NN * KNN * 4;   // 2 MB
    const size_t WCF_B  = 512 * 64 * 2;                // 64 KB
    const size_t W2F_B  = 256 * 128 * 2;               // 64 KB
    const size_t G_B    = (size_t)BB * NN * H2 * 2;    // 16 MB

    int* knn_idx = (int*)d_ws;
    char* p = (char*)d_ws + IDX_B;
    _Float16* Wcf  = (_Float16*)p;  p += WCF_B;
    _Float16* W2f  = (_Float16*)p;  p += W2F_B;
    _Float16* Gall = (_Float16*)p;  p += G_B;
    _Float16* Qall = (_Float16*)p;                     // 16 MB -> total ~34.1 MB

    prep_weights<<<16, 512, 0, stream>>>(W1, W2, Wcf, W2f);
    knn_gq<<<5120, 512, 0, stream>>>(points, knn_idx, features, Wcf, b1, Gall, Qall);
    fused_mlp17<<<2048, 512, 0, stream>>>(Gall, Qall, knn_idx, W2f, b2, out);
}

// Round 12
// 184.051 us; speedup vs baseline: 1.0225x; 1.0024x over previous
//
#include <hip/hip_runtime.h>
#include <math.h>

#define BB 32
#define NN 1024
#define FF 64
#define PP 128
#define KNN 16
#define H2 256  // 2P
#define F2 128  // 2F
#define KSEL 17
#define SVCAP 272

typedef float f32x4 __attribute__((ext_vector_type(4)));
typedef _Float16 f16x8 __attribute__((ext_vector_type(8)));
typedef _Float16 f16x4 __attribute__((ext_vector_type(4)));
typedef _Float16 f16x2 __attribute__((ext_vector_type(2)));

// ---- transcendental-free gelu: y = x * (0.5 + xc*P(xc^2)), xc = clamp(x, +-3.3)
#define GC1 0.39616247f
#define GC3 -0.05891477f
#define GC5 0.00563735f
#define GC7 -2.10439e-4f
#define GXC 3.2988f

__device__ __forceinline__ f16x8 splat8(float f) {
    _Float16 h = (_Float16)f;
    f16x8 v = {h, h, h, h, h, h, h, h};
    return v;
}
__device__ __forceinline__ f16x4 splat4(float f) {
    _Float16 h = (_Float16)f;
    f16x4 v = {h, h, h, h};
    return v;
}

// packed-f16 activation for 8 elements: gelu(g + q); v_pk_{add,mul,fma,min,max}_f16
__device__ __forceinline__ f16x8 act8(f16x8 gv, f16x8 qv) {
    const f16x8 XL = splat8(-GXC), XH = splat8(GXC);
    const f16x8 C1 = splat8(GC1), C3 = splat8(GC3), C5 = splat8(GC5), C7 = splat8(GC7);
    const f16x8 HF = splat8(0.5f);
    f16x8 x  = gv + qv;
    f16x8 xc = __builtin_elementwise_min(__builtin_elementwise_max(x, XL), XH);
    f16x8 s  = xc * xc;
    f16x8 t  = s * C7 + C5;
    t = s * t + C3;
    t = s * t + C1;
    f16x8 u = xc * t + HF;
    return x * u;
}

// packed-f16 epilogue: sum_r gelu(acc[r] + bias) over the 4 in-lane k-rows
__device__ __forceinline__ float gelu4_sum(f32x4 a, float bias) {
    f16x4 x;
    x[0] = (_Float16)(a[0] + bias);
    x[1] = (_Float16)(a[1] + bias);
    x[2] = (_Float16)(a[2] + bias);
    x[3] = (_Float16)(a[3] + bias);
    const f16x4 XL = splat4(-GXC), XH = splat4(GXC);
    const f16x4 C1 = splat4(GC1), C3 = splat4(GC3), C5 = splat4(GC5), C7 = splat4(GC7);
    const f16x4 HF = splat4(0.5f);
    f16x4 xc = __builtin_elementwise_min(__builtin_elementwise_max(x, XL), XH);
    f16x4 s  = xc * xc;
    f16x4 t  = s * C7 + C5;
    t = s * t + C3;
    t = s * t + C1;
    f16x4 u = xc * t + HF;
    f16x4 y = x * u;
    f16x2 y2 = __builtin_shufflevector(y, y, 0, 1) + __builtin_shufflevector(y, y, 2, 3);
    return (float)y2[0] + (float)y2[1];
}

// async global->LDS, 16B/lane: per-lane GLOBAL address, wave-uniform LDS base + lane*16.
// The LDS write is a side effect the compiler cannot roll back to the use site.
__device__ __forceinline__ void gld16(const void* g, void* l) {
    __builtin_amdgcn_global_load_lds((const __attribute__((address_space(1))) unsigned int*)g,
                                     (__attribute__((address_space(3))) unsigned int*)l,
                                     16, 0, 0);
}

// ------- prep_weights: fragment-swizzled Wcf (gq B-operand) + W2f (fused B) --------
__global__ __launch_bounds__(512) void prep_weights(const float* __restrict__ W1,
                                                    const float* __restrict__ W2,
                                                    _Float16* __restrict__ Wcf,
                                                    _Float16* __restrict__ W2f) {
    int tid = blockIdx.x * 512 + threadIdx.x;   // 0..8191
    if (tid < 4096) {
        const int lane = tid & 63, quad = lane >> 4, l16 = lane & 15;
        const int kk = (tid >> 6) & 1, n_tile = tid >> 7;
        const int n = n_tile * 16 + l16;
        const int kb = kk * 32 + quad * 8;
        f16x8 v;
#pragma unroll
        for (int j = 0; j < 8; ++j) {
            const int k = kb + j;
            float x = (n < 256) ? W1[k * 256 + n]
                                : (W1[(64 + k) * 256 + (n - 256)] - W1[k * 256 + (n - 256)]);
            v[j] = (_Float16)x;
        }
        *(f16x8*)(Wcf + (size_t)tid * 8) = v;
    } else {
        const int t2 = tid - 4096;
        const int lane = t2 & 63, quad = lane >> 4, l16 = lane & 15;
        const int nt = (t2 >> 6) & 7, kk8 = t2 >> 9;
        const int p = nt * 16 + l16;
        const int hb = kk8 * 32 + quad * 8;
        f16x8 v;
#pragma unroll
        for (int j = 0; j < 8; ++j) v[j] = (_Float16)W2[(size_t)(hb + j) * PP + p];
        *(f16x8*)(W2f + (size_t)t2 * 8) = v;
    }
}

// ------- knn_gq: blocks 0..4095 = set-based kNN; 4096..5119 = G/Q GEMM -------------
// (verbatim R9-R11 version: XCD writer/reader alignment + register-cached survivors)
__global__ __launch_bounds__(512, 8) void knn_gq(const float* __restrict__ points,
                                                 int* __restrict__ idx_out,
                                                 const float* __restrict__ feat,
                                                 const _Float16* __restrict__ Wcf,
                                                 const float* __restrict__ b1,
                                                 _Float16* __restrict__ Gall,
                                                 _Float16* __restrict__ Qall) {
    __shared__ __align__(16) unsigned char smem[35840];
    const int t = threadIdx.x;

    if (blockIdx.x >= 4096) {
        _Float16 (*st)[16][136] = (_Float16(*)[16][136])smem;
        const int w8 = t >> 6, lane = t & 63;
        const int w4 = w8 & 3;
        const int quad = lane >> 4, l16 = lane & 15;
        const int gb = blockIdx.x - 4096;
        const int gbl = ((gb & 7) << 7) | (gb >> 3);
        const int m0 = gbl * 32 + (w8 >> 2) * 16;

        f16x8 a[2];
#pragma unroll
        for (int kk = 0; kk < 2; ++kk) {
            const float* ap = feat + (size_t)(m0 + l16) * 64 + kk * 32 + quad * 8;
            float4 a0 = *(const float4*)ap, a1 = *(const float4*)(ap + 4);
            f16x8 v;
            v[0] = (_Float16)a0.x; v[1] = (_Float16)a0.y; v[2] = (_Float16)a0.z; v[3] = (_Float16)a0.w;
            v[4] = (_Float16)a1.x; v[5] = (_Float16)a1.y; v[6] = (_Float16)a1.z; v[7] = (_Float16)a1.w;
            a[kk] = v;
        }
        f32x4 acc[8];
#pragma unroll
        for (int nt = 0; nt < 8; ++nt) acc[nt] = (f32x4){0.f, 0.f, 0.f, 0.f};
#pragma unroll
        for (int kk = 0; kk < 2; ++kk)
#pragma unroll
            for (int nt = 0; nt < 8; ++nt) {
                f16x8 bf = *(const f16x8*)(Wcf + (size_t)(((w4 * 8 + nt) * 2 + kk) * 64 + lane) * 8);
                acc[nt] = __builtin_amdgcn_mfma_f32_16x16x32_f16(a[kk], bf, acc[nt], 0, 0, 0);
            }

        const bool isQ = (w4 >= 2);
#pragma unroll
        for (int nt = 0; nt < 8; ++nt) {
            const int col = nt * 16 + l16;
            const float bias = isQ ? b1[(w4 - 2) * 128 + col] : 0.f;
#pragma unroll
            for (int r = 0; r < 4; ++r)
                st[w8][quad * 4 + r][col] = (_Float16)(acc[nt][r] + bias);
        }
        __syncthreads();

        const int row = lane >> 2, c = lane & 3;
        const int m = m0 + row;
#pragma unroll
        for (int i = 0; i < 4; ++i) {
            const int col = c * 32 + i * 8;
            f16x8 v = *(const f16x8*)&st[w8][row][col];
            if (!isQ) *(f16x8*)(Gall + (size_t)m * H2 + w4 * 128 + col) = v;
            else      *(f16x8*)(Qall + (size_t)m * H2 + (w4 - 2) * 128 + col) = v;
        }
        return;
    }

    float2* pxy = (float2*)smem;
    float2* pzr = (float2*)(smem + 8192);
    unsigned (*sv_val)[SVCAP] = (unsigned(*)[SVCAP])(smem + 16384);
    unsigned (*sv_idx)[SVCAP] = (unsigned(*)[SVCAP])(smem + 25088);
    unsigned (*tie_idx)[64]   = (unsigned(*)[64])(smem + 33792);

    const int lbk = ((blockIdx.x & 7) << 9) | (blockIdx.x >> 3);

    const int w = t >> 6, lane = t & 63;
    const int b = lbk >> 7;
    const int q0 = (lbk & 127) * 8;
    const float* pb = points + (size_t)b * NN * 3;
    const unsigned long long lt = (1ull << lane) - 1ull;

    for (int i = t; i < NN; i += 512) {
        float x = pb[3 * i], y = pb[3 * i + 1], z = pb[3 * i + 2];
        float r = __fadd_rn(__fadd_rn(__fmul_rn(x, x), __fmul_rn(y, y)), __fmul_rn(z, z));
        pxy[i] = make_float2(x, y);
        pzr[i] = make_float2(z, r);
    }
    __syncthreads();

    const int qn = q0 + w;
    const int gq = b * NN + qn;
    const float2 qv1 = pxy[qn], qv2 = pzr[qn];
    const float qx = qv1.x, qy = qv1.y, qz = qv2.x, qw = qv2.y;

    float D[16];
#pragma unroll
    for (int j = 0; j < 16; ++j) {
        const int m = j * 64 + lane;
        const float2 v1 = pxy[m], v2 = pzr[m];
        float dot = __fadd_rn(__fadd_rn(__fmul_rn(qx, v1.x), __fmul_rn(qy, v1.y)),
                              __fmul_rn(qz, v2.x));
        D[j] = __fadd_rn(__fadd_rn(__fsub_rn(qw, __fmul_rn(2.0f, dot)), v2.y), 1e-5f);
    }

    float mnf = D[0];
#pragma unroll
    for (int j = 1; j < 16; ++j) mnf = fminf(mnf, D[j]);
    const unsigned mbits = __float_as_uint(mnf);

    const unsigned mhi = mbits >> 16;
    unsigned Thi = 0;
#pragma unroll
    for (int bit = 15; bit >= 0; --bit) {
        unsigned cand = Thi | (1u << bit);
        int cnt = __popcll(__ballot(mhi < cand));
        if (cnt < KSEL) Thi = cand;
    }
    const unsigned T = (Thi << 16) | 0xFFFFu;

    unsigned base = 0;
#pragma unroll
    for (int j = 0; j < 16; ++j) {
        unsigned vb = __float_as_uint(D[j]);
        bool keep = (vb <= T);
        unsigned long long m = __ballot(keep);
        if (keep) {
            unsigned pos = base + (unsigned)__popcll(m & lt);
            if (pos < SVCAP) { sv_val[w][pos] = vb; sv_idx[w][pos] = j * 64 + lane; }
        }
        base += (unsigned)__popcll(m);
    }
    unsigned C = base > SVCAP ? SVCAP : base;

    unsigned rv[5], ri[5];
#pragma unroll
    for (int s = 0; s < 5; ++s) {
        int i = s * 64 + lane;
        bool ok = (i < (int)C);
        rv[s] = ok ? sv_val[w][i] : 0xFFFFFFFFu;
        ri[s] = ok ? sv_idx[w][i] : 0xFFFFFFFFu;
    }

    unsigned Ts = 0;
    if (C <= 64) {
#pragma unroll
        for (int bit = 31; bit >= 0; --bit) {
            unsigned cand = Ts | (1u << bit);
            int cnt = __popcll(__ballot(rv[0] < cand));
            if (cnt < KSEL) Ts = cand;
        }
    } else {
#pragma unroll
        for (int bit = 31; bit >= 0; --bit) {
            unsigned cand = Ts | (1u << bit);
            int cnt = 0;
#pragma unroll
            for (int s = 0; s < 5; ++s)
                cnt += __popcll(__ballot(rv[s] < cand));
            if (cnt < KSEL) Ts = cand;
        }
    }

    int L = 0;
#pragma unroll
    for (int s = 0; s < 5; ++s) L += __popcll(__ballot(rv[s] < Ts));
    const int need = KSEL - L;

    unsigned vmin_l = 0xFFFFFFFFu;
#pragma unroll
    for (int s = 0; s < 5; ++s) vmin_l = vmin_l < rv[s] ? vmin_l : rv[s];
#pragma unroll
    for (int off = 32; off >= 1; off >>= 1) {
        unsigned o2 = __shfl_xor(vmin_l, off, 64);
        vmin_l = vmin_l < o2 ? vmin_l : o2;
    }
    const unsigned Vmin = vmin_l;
    unsigned imin_l = 0xFFFFFFFFu;
#pragma unroll
    for (int s = 0; s < 5; ++s)
        if (rv[s] == Vmin && ri[s] < imin_l) imin_l = ri[s];
#pragma unroll
    for (int off = 32; off >= 1; off >>= 1) {
        unsigned o2 = __shfl_xor(imin_l, off, 64);
        imin_l = imin_l < o2 ? imin_l : o2;
    }
    const unsigned dropIdx = imin_l;

    int* o = idx_out + (size_t)gq * KNN;
    unsigned wbase = 0, tbase = 0;
#pragma unroll
    for (int s = 0; s < 5; ++s) {
        unsigned vb = rv[s], mi = ri[s];
        bool wk = (vb < Ts) && (mi != dropIdx);
        unsigned long long wm = __ballot(wk);
        if (wk) o[wbase + (unsigned)__popcll(wm & lt)] = (int)mi;
        wbase += (unsigned)__popcll(wm);
        bool tk = (vb == Ts);
        unsigned long long tm2 = __ballot(tk);
        if (tk) {
            unsigned tp = tbase + (unsigned)__popcll(tm2 & lt);
            if (tp < 64) tie_idx[w][tp] = mi;
        }
        tbase += (unsigned)__popcll(tm2);
    }
    unsigned tc = tbase > 64 ? 64 : tbase;
    if ((int)tc == need) {
        bool tk = (lane < (int)tc);
        unsigned mi2 = tk ? tie_idx[w][lane] : 0xFFFFFFFFu;
        tk = tk && (mi2 != dropIdx);
        unsigned long long m3 = __ballot(tk);
        if (tk) o[wbase + (unsigned)__popcll(m3 & lt)] = (int)mi2;
    } else if (lane == 0) {
        unsigned pos = wbase;
        for (int r = 0; r < need; ++r) {
            unsigned best = 0xFFFFFFFFu; int bj = 0;
            for (int j2 = 0; j2 < (int)tc; ++j2) {
                unsigned mi = tie_idx[w][j2];
                if (mi < best) { best = mi; bj = j2; }
            }
            tie_idx[w][bj] = 0xFFFFFFFFu;
            if (best != dropIdx) o[pos++] = (int)best;
        }
    }
}

// ---------------- fused_mlp18: out = mean_k gelu(gelu(G[idx]+Q) @ W2 + b2) ----------
// mlp17 (71.5 us champion) + two tail/latency changes:
//  1. Shuffle-free epilogue: each quad writes its partial gelu4_sum to obuf[4][2048]
//     (aliasing w2s, 32 KB exact), one barrier, then each thread sums 4 f32x4 rows
//     and stores coalesced. Removes 32 serial ds_bpermute shuffles per wave.
//  2. G prefetch issued BEFORE act8 (after the anti-dependent slot reads) -> +~100
//     cyc of latency cover per rk. vmcnt counting invariant unchanged (2 in flight).
__global__ __launch_bounds__(512, 3) void fused_mlp18(const _Float16* __restrict__ Gall,
                                                      const _Float16* __restrict__ Qall,
                                                      const int* __restrict__ knn_idx,
                                                      const _Float16* __restrict__ W2f,
                                                      const float* __restrict__ b2,
                                                      float* __restrict__ out) {
    __shared__ __align__(16) _Float16 w2s[16384];        // 32 KB: half of W2f / obuf
    __shared__ __align__(16) _Float16 gbuf[8][2][1024];  // 32 KB: per-wave G dbuf
    __shared__ __align__(16) _Float16 qbuf[8][512];      //  8 KB: per-wave Q rows
    const int t = threadIdx.x, w = t >> 6, lane = t & 63;
    const int quad = lane >> 4, l16 = lane & 15;

    const int lb = ((blockIdx.x & 7) << 8) | (blockIdx.x >> 3);

    const int q0 = lb * 16 + w * 2;
    const int b = q0 >> 10;
    const int nb0 = knn_idx[q0 * KNN + l16];
    const int nb1 = knn_idx[(q0 + 1) * KNN + l16];
    const _Float16* g0 = Gall + ((size_t)(b << 10) + nb0) * H2;
    const _Float16* g1 = Gall + ((size_t)(b << 10) + nb1) * H2;

    // per-lane byte addresses
    const char* aG0 = (const char*)g0 + quad * 16;
    const char* aG1 = (const char*)g1 + quad * 16;
    const char* aQ  = (const char*)(Qall + (size_t)q0 * H2) + (lane >> 5) * (H2 * 2) + (lane & 31) * 16;
    const char* w2b = (const char*)W2f;

    // ---- prologue: stage Q (1 instr), W2f half0 (4), G pairs rk0/rk1 (4) ----
    gld16(aQ, &qbuf[w][0]);
#pragma unroll
    for (int i = 0; i < 4; ++i)
        gld16(w2b + i * 8192 + w * 1024 + lane * 16, &w2s[i * 4096 + w * 512]);
    gld16(aG0,      &gbuf[w][0][0]);
    gld16(aG1,      &gbuf[w][0][512]);
    gld16(aG0 + 64, &gbuf[w][1][0]);
    gld16(aG1 + 64, &gbuf[w][1][512]);

    f32x4 acc[2][8];
#pragma unroll
    for (int tm = 0; tm < 2; ++tm)
#pragma unroll
        for (int nt = 0; nt < 8; ++nt) acc[tm][nt] = (f32x4){0.f, 0.f, 0.f, 0.f};

    __syncthreads();   // drains all prologue loads (vmcnt(0) implied)

#define STEP(RK, WN)                                                                   \
    {                                                                                  \
        asm volatile("s_waitcnt vmcnt(%c0)" ::"i"(WN) : "memory");                     \
        f16x8 gA = *(const f16x8*)&gbuf[w][(RK) & 1][lane * 8];                        \
        f16x8 gB = *(const f16x8*)&gbuf[w][(RK) & 1][512 + lane * 8];                  \
        f16x8 qA = *(const f16x8*)&qbuf[w][(RK) * 32 + quad * 8];                      \
        f16x8 qB = *(const f16x8*)&qbuf[w][256 + (RK) * 32 + quad * 8];                \
        if ((RK) < 6) {                                                                \
            gld16(aG0 + ((RK) + 2) * 64, &gbuf[w][(RK) & 1][0]);                       \
            gld16(aG1 + ((RK) + 2) * 64, &gbuf[w][(RK) & 1][512]);                     \
        }                                                                              \
        f16x8 a0 = act8(gA, qA);                                                       \
        f16x8 a1 = act8(gB, qB);                                                       \
        const _Float16* bb = &w2s[((RK) & 3) * 4096 + lane * 8];                       \
        _Pragma("unroll")                                                              \
        for (int nt = 0; nt < 8; ++nt) {                                               \
            f16x8 bf = *(const f16x8*)(bb + nt * 512);                                 \
            acc[0][nt] = __builtin_amdgcn_mfma_f32_16x16x32_f16(a0, bf, acc[0][nt], 0, 0, 0); \
            acc[1][nt] = __builtin_amdgcn_mfma_f32_16x16x32_f16(a1, bf, acc[1][nt], 0, 0, 0); \
        }                                                                              \
    }

    STEP(0, 2) STEP(1, 2) STEP(2, 2) STEP(3, 2)

    // ---- mid-phase: swap in W2f half1 (barriers drain in-flight prefetches) ----
    __syncthreads();
#pragma unroll
    for (int i = 0; i < 4; ++i)
        gld16(w2b + 32768 + i * 8192 + w * 1024 + lane * 16, &w2s[i * 4096 + w * 512]);
    __syncthreads();

    STEP(4, 2) STEP(5, 2) STEP(6, 2) STEP(7, 0)
#undef STEP

    // ---- shuffle-free epilogue: quad partials in obuf[4][2048] (aliases w2s) ----
    __syncthreads();
    float* obuf = (float*)w2s;       // 4 * 2048 * 4B = 32 KB exact
#pragma unroll
    for (int tm = 0; tm < 2; ++tm)
#pragma unroll
        for (int nt = 0; nt < 8; ++nt) {
            const float bias = b2[nt * 16 + l16];
            float s = gelu4_sum(acc[tm][nt], bias);
            obuf[quad * 2048 + (w * 2 + tm) * 128 + nt * 16 + l16] = s;
        }
    __syncthreads();
    {
        // block covers queries [lb*16, lb*16+16): sum 4 quad-partials, store 16B/thread
        const float* o0 = obuf + t * 4;
        f32x4 v0 = *(const f32x4*)(o0);
        f32x4 v1 = *(const f32x4*)(o0 + 2048);
        f32x4 v2 = *(const f32x4*)(o0 + 4096);
        f32x4 v3 = *(const f32x4*)(o0 + 6144);
        f32x4 vs = ((v0 + v1) + (v2 + v3)) * 0.0625f;
        *(f32x4*)(out + (size_t)lb * 2048 + t * 4) = vs;
    }
}

extern "C" void kernel_launch(void* const* d_in, const int* in_sizes, int n_in,
                              void* d_out, int out_size, void* d_ws, size_t ws_size,
                              hipStream_t stream) {
    const float* points   = (const float*)d_in[0];
    const float* features = (const float*)d_in[1];
    const float* W1 = (const float*)d_in[2];
    const float* b1 = (const float*)d_in[3];
    const float* W2 = (const float*)d_in[4];
    const float* b2 = (const float*)d_in[5];
    float* out = (float*)d_out;

    const size_t IDX_B  = (size_t)BB * NN * KNN * 4;   // 2 MB
    const size_t WCF_B  = 512 * 64 * 2;                // 64 KB
    const size_t W2F_B  = 256 * 128 * 2;               // 64 KB
    const size_t G_B    = (size_t)BB * NN * H2 * 2;    // 16 MB

    int* knn_idx = (int*)d_ws;
    char* p = (char*)d_ws + IDX_B;
    _Float16* Wcf  = (_Float16*)p;  p += WCF_B;
    _Float16* W2f  = (_Float16*)p;  p += W2F_B;
    _Float16* Gall = (_Float16*)p;  p += G_B;
    _Float16* Qall = (_Float16*)p;                     // 16 MB -> total ~34.1 MB

    prep_weights<<<16, 512, 0, stream>>>(W1, W2, Wcf, W2f);
    knn_gq<<<5120, 512, 0, stream>>>(points, knn_idx, features, Wcf, b1, Gall, Qall);
    fused_mlp18<<<2048, 512, 0, stream>>>(Gall, Qall, knn_idx, W2f, b2, out);
}

// Round 13
// 183.110 us; speedup vs baseline: 1.0278x; 1.0051x over previous
//
#include <hip/hip_runtime.h>
#include <math.h>

#define BB 32
#define NN 1024
#define FF 64
#define PP 128
#define KNN 16
#define H2 256  // 2P
#define F2 128  // 2F
#define KSEL 17
#define SVCAP 272

typedef float f32x4 __attribute__((ext_vector_type(4)));
typedef _Float16 f16x8 __attribute__((ext_vector_type(8)));
typedef _Float16 f16x4 __attribute__((ext_vector_type(4)));
typedef _Float16 f16x2 __attribute__((ext_vector_type(2)));

// ---- transcendental-free gelu: y = x * (0.5 + xc*P(xc^2)), xc = clamp(x, +-3.3)
#define GC1 0.39616247f
#define GC3 -0.05891477f
#define GC5 0.00563735f
#define GC7 -2.10439e-4f
#define GXC 3.2988f

__device__ __forceinline__ f16x8 splat8(float f) {
    _Float16 h = (_Float16)f;
    f16x8 v = {h, h, h, h, h, h, h, h};
    return v;
}
__device__ __forceinline__ f16x4 splat4(float f) {
    _Float16 h = (_Float16)f;
    f16x4 v = {h, h, h, h};
    return v;
}

// packed-f16 activation for 8 elements: gelu(g + q); v_pk_{add,mul,fma,min,max}_f16
__device__ __forceinline__ f16x8 act8(f16x8 gv, f16x8 qv) {
    const f16x8 XL = splat8(-GXC), XH = splat8(GXC);
    const f16x8 C1 = splat8(GC1), C3 = splat8(GC3), C5 = splat8(GC5), C7 = splat8(GC7);
    const f16x8 HF = splat8(0.5f);
    f16x8 x  = gv + qv;
    f16x8 xc = __builtin_elementwise_min(__builtin_elementwise_max(x, XL), XH);
    f16x8 s  = xc * xc;
    f16x8 t  = s * C7 + C5;
    t = s * t + C3;
    t = s * t + C1;
    f16x8 u = xc * t + HF;
    return x * u;
}

// packed-f16 epilogue: sum_r gelu(acc[r] + bias) over the 4 in-lane k-rows
__device__ __forceinline__ float gelu4_sum(f32x4 a, float bias) {
    f16x4 x;
    x[0] = (_Float16)(a[0] + bias);
    x[1] = (_Float16)(a[1] + bias);
    x[2] = (_Float16)(a[2] + bias);
    x[3] = (_Float16)(a[3] + bias);
    const f16x4 XL = splat4(-GXC), XH = splat4(GXC);
    const f16x4 C1 = splat4(GC1), C3 = splat4(GC3), C5 = splat4(GC5), C7 = splat4(GC7);
    const f16x4 HF = splat4(0.5f);
    f16x4 xc = __builtin_elementwise_min(__builtin_elementwise_max(x, XL), XH);
    f16x4 s  = xc * xc;
    f16x4 t  = s * C7 + C5;
    t = s * t + C3;
    t = s * t + C1;
    f16x4 u = xc * t + HF;
    f16x4 y = x * u;
    f16x2 y2 = __builtin_shufflevector(y, y, 0, 1) + __builtin_shufflevector(y, y, 2, 3);
    return (float)y2[0] + (float)y2[1];
}

// async global->LDS, 16B/lane: per-lane GLOBAL address, wave-uniform LDS base + lane*16.
// The LDS write is a side effect the compiler cannot roll back to the use site.
__device__ __forceinline__ void gld16(const void* g, void* l) {
    __builtin_amdgcn_global_load_lds((const __attribute__((address_space(1))) unsigned int*)g,
                                     (__attribute__((address_space(3))) unsigned int*)l,
                                     16, 0, 0);
}

// ------- prep_weights: fragment-swizzled Wcf (gq B-operand) + W2f (fused B) --------
__global__ __launch_bounds__(512) void prep_weights(const float* __restrict__ W1,
                                                    const float* __restrict__ W2,
                                                    _Float16* __restrict__ Wcf,
                                                    _Float16* __restrict__ W2f) {
    int tid = blockIdx.x * 512 + threadIdx.x;   // 0..8191
    if (tid < 4096) {
        const int lane = tid & 63, quad = lane >> 4, l16 = lane & 15;
        const int kk = (tid >> 6) & 1, n_tile = tid >> 7;
        const int n = n_tile * 16 + l16;
        const int kb = kk * 32 + quad * 8;
        f16x8 v;
#pragma unroll
        for (int j = 0; j < 8; ++j) {
            const int k = kb + j;
            float x = (n < 256) ? W1[k * 256 + n]
                                : (W1[(64 + k) * 256 + (n - 256)] - W1[k * 256 + (n - 256)]);
            v[j] = (_Float16)x;
        }
        *(f16x8*)(Wcf + (size_t)tid * 8) = v;
    } else {
        const int t2 = tid - 4096;
        const int lane = t2 & 63, quad = lane >> 4, l16 = lane & 15;
        const int nt = (t2 >> 6) & 7, kk8 = t2 >> 9;
        const int p = nt * 16 + l16;
        const int hb = kk8 * 32 + quad * 8;
        f16x8 v;
#pragma unroll
        for (int j = 0; j < 8; ++j) v[j] = (_Float16)W2[(size_t)(hb + j) * PP + p];
        *(f16x8*)(W2f + (size_t)t2 * 8) = v;
    }
}

// ------- knn_gq: blocks 0..2047 = set-based kNN (2 queries/wave, 16/block);
//                 blocks 2048..3071 = G/Q GEMM ---------------------------------------
// 2 queries/wave halves kNN block count: point staging (12 KB/block) + barrier are
// amortized over 16 queries instead of 8, and dispatch rounds drop 5 -> 3.
// Select math per query is bit-identical (serial qi loop inside the wave).
// XCD writer/reader alignment kept: XCD x writes batches [4x,4x+4) which fused reads.
__global__ __launch_bounds__(512, 8) void knn_gq(const float* __restrict__ points,
                                                 int* __restrict__ idx_out,
                                                 const float* __restrict__ feat,
                                                 const _Float16* __restrict__ Wcf,
                                                 const float* __restrict__ b1,
                                                 _Float16* __restrict__ Gall,
                                                 _Float16* __restrict__ Qall) {
    __shared__ __align__(16) unsigned char smem[35840];
    const int t = threadIdx.x;

    if (blockIdx.x >= 2048) {
        _Float16 (*st)[16][136] = (_Float16(*)[16][136])smem;
        const int w8 = t >> 6, lane = t & 63;
        const int w4 = w8 & 3;
        const int quad = lane >> 4, l16 = lane & 15;
        const int gb = blockIdx.x - 2048;            // 0..1023; XCD = gb % 8
        const int gbl = ((gb & 7) << 7) | (gb >> 3); // XCD x -> rows of batches [4x,4x+4)
        const int m0 = gbl * 32 + (w8 >> 2) * 16;

        f16x8 a[2];
#pragma unroll
        for (int kk = 0; kk < 2; ++kk) {
            const float* ap = feat + (size_t)(m0 + l16) * 64 + kk * 32 + quad * 8;
            float4 a0 = *(const float4*)ap, a1 = *(const float4*)(ap + 4);
            f16x8 v;
            v[0] = (_Float16)a0.x; v[1] = (_Float16)a0.y; v[2] = (_Float16)a0.z; v[3] = (_Float16)a0.w;
            v[4] = (_Float16)a1.x; v[5] = (_Float16)a1.y; v[6] = (_Float16)a1.z; v[7] = (_Float16)a1.w;
            a[kk] = v;
        }
        f32x4 acc[8];
#pragma unroll
        for (int nt = 0; nt < 8; ++nt) acc[nt] = (f32x4){0.f, 0.f, 0.f, 0.f};
#pragma unroll
        for (int kk = 0; kk < 2; ++kk)
#pragma unroll
            for (int nt = 0; nt < 8; ++nt) {
                f16x8 bf = *(const f16x8*)(Wcf + (size_t)(((w4 * 8 + nt) * 2 + kk) * 64 + lane) * 8);
                acc[nt] = __builtin_amdgcn_mfma_f32_16x16x32_f16(a[kk], bf, acc[nt], 0, 0, 0);
            }

        const bool isQ = (w4 >= 2);
#pragma unroll
        for (int nt = 0; nt < 8; ++nt) {
            const int col = nt * 16 + l16;
            const float bias = isQ ? b1[(w4 - 2) * 128 + col] : 0.f;
#pragma unroll
            for (int r = 0; r < 4; ++r)
                st[w8][quad * 4 + r][col] = (_Float16)(acc[nt][r] + bias);
        }
        __syncthreads();

        const int row = lane >> 2, c = lane & 3;
        const int m = m0 + row;
#pragma unroll
        for (int i = 0; i < 4; ++i) {
            const int col = c * 32 + i * 8;
            f16x8 v = *(const f16x8*)&st[w8][row][col];
            if (!isQ) *(f16x8*)(Gall + (size_t)m * H2 + w4 * 128 + col) = v;
            else      *(f16x8*)(Qall + (size_t)m * H2 + (w4 - 2) * 128 + col) = v;
        }
        return;
    }

    float2* pxy = (float2*)smem;
    float2* pzr = (float2*)(smem + 8192);
    unsigned (*sv_val)[SVCAP] = (unsigned(*)[SVCAP])(smem + 16384);
    unsigned (*sv_idx)[SVCAP] = (unsigned(*)[SVCAP])(smem + 25088);
    unsigned (*tie_idx)[64]   = (unsigned(*)[64])(smem + 33792);

    // XCD-align with fused: 2048 kNN blocks, XCD x owns lbk in [256x,256x+256)
    // = batches [4x,4x+4) (64 blocks/batch, 16 queries/block).
    const int lbk = ((blockIdx.x & 7) << 8) | (blockIdx.x >> 3);

    const int w = t >> 6, lane = t & 63;
    const int b = lbk >> 6;
    const int qb = (lbk & 63) * 16;
    const float* pb = points + (size_t)b * NN * 3;
    const unsigned long long lt = (1ull << lane) - 1ull;

    for (int i = t; i < NN; i += 512) {
        float x = pb[3 * i], y = pb[3 * i + 1], z = pb[3 * i + 2];
        float r = __fadd_rn(__fadd_rn(__fmul_rn(x, x), __fmul_rn(y, y)), __fmul_rn(z, z));
        pxy[i] = make_float2(x, y);
        pzr[i] = make_float2(z, r);
    }
    __syncthreads();

    for (int qi = 0; qi < 2; ++qi) {
        const int qn = qb + w * 2 + qi;
        const int gq = b * NN + qn;
        const float2 qv1 = pxy[qn], qv2 = pzr[qn];
        const float qx = qv1.x, qy = qv1.y, qz = qv2.x, qw = qv2.y;

        float D[16];
#pragma unroll
        for (int j = 0; j < 16; ++j) {
            const int m = j * 64 + lane;
            const float2 v1 = pxy[m], v2 = pzr[m];
            float dot = __fadd_rn(__fadd_rn(__fmul_rn(qx, v1.x), __fmul_rn(qy, v1.y)),
                                  __fmul_rn(qz, v2.x));
            D[j] = __fadd_rn(__fadd_rn(__fsub_rn(qw, __fmul_rn(2.0f, dot)), v2.y), 1e-5f);
        }

        float mnf = D[0];
#pragma unroll
        for (int j = 1; j < 16; ++j) mnf = fminf(mnf, D[j]);
        const unsigned mbits = __float_as_uint(mnf);

        // T_ub via 16-round radix on the HIGH 16 bits of the lane-mins.
        const unsigned mhi = mbits >> 16;
        unsigned Thi = 0;
#pragma unroll
        for (int bit = 15; bit >= 0; --bit) {
            unsigned cand = Thi | (1u << bit);
            int cnt = __popcll(__ballot(mhi < cand));
            if (cnt < KSEL) Thi = cand;
        }
        const unsigned T = (Thi << 16) | 0xFFFFu;

        unsigned base = 0;
#pragma unroll
        for (int j = 0; j < 16; ++j) {
            unsigned vb = __float_as_uint(D[j]);
            bool keep = (vb <= T);
            unsigned long long m = __ballot(keep);
            if (keep) {
                unsigned pos = base + (unsigned)__popcll(m & lt);
                if (pos < SVCAP) { sv_val[w][pos] = vb; sv_idx[w][pos] = j * 64 + lane; }
            }
            base += (unsigned)__popcll(m);
        }
        unsigned C = base > SVCAP ? SVCAP : base;

        // register-cache survivors (<=5 slots/lane); later loops are register-only.
        unsigned rv[5], ri[5];
#pragma unroll
        for (int s = 0; s < 5; ++s) {
            int i = s * 64 + lane;
            bool ok = (i < (int)C);
            rv[s] = ok ? sv_val[w][i] : 0xFFFFFFFFu;
            ri[s] = ok ? sv_idx[w][i] : 0xFFFFFFFFu;
        }

        unsigned Ts = 0;
        if (C <= 64) {
#pragma unroll
            for (int bit = 31; bit >= 0; --bit) {
                unsigned cand = Ts | (1u << bit);
                int cnt = __popcll(__ballot(rv[0] < cand));
                if (cnt < KSEL) Ts = cand;
            }
        } else {
#pragma unroll
            for (int bit = 31; bit >= 0; --bit) {
                unsigned cand = Ts | (1u << bit);
                int cnt = 0;
#pragma unroll
                for (int s = 0; s < 5; ++s)
                    cnt += __popcll(__ballot(rv[s] < cand));
                if (cnt < KSEL) Ts = cand;
            }
        }

        int L = 0;
#pragma unroll
        for (int s = 0; s < 5; ++s) L += __popcll(__ballot(rv[s] < Ts));
        const int need = KSEL - L;

        unsigned vmin_l = 0xFFFFFFFFu;
#pragma unroll
        for (int s = 0; s < 5; ++s) vmin_l = vmin_l < rv[s] ? vmin_l : rv[s];
#pragma unroll
        for (int off = 32; off >= 1; off >>= 1) {
            unsigned o2 = __shfl_xor(vmin_l, off, 64);
            vmin_l = vmin_l < o2 ? vmin_l : o2;
        }
        const unsigned Vmin = vmin_l;
        unsigned imin_l = 0xFFFFFFFFu;
#pragma unroll
        for (int s = 0; s < 5; ++s)
            if (rv[s] == Vmin && ri[s] < imin_l) imin_l = ri[s];
#pragma unroll
        for (int off = 32; off >= 1; off >>= 1) {
            unsigned o2 = __shfl_xor(imin_l, off, 64);
            imin_l = imin_l < o2 ? imin_l : o2;
        }
        const unsigned dropIdx = imin_l;

        int* o = idx_out + (size_t)gq * KNN;
        unsigned wbase = 0, tbase = 0;
#pragma unroll
        for (int s = 0; s < 5; ++s) {
            unsigned vb = rv[s], mi = ri[s];
            bool wk = (vb < Ts) && (mi != dropIdx);
            unsigned long long wm = __ballot(wk);
            if (wk) o[wbase + (unsigned)__popcll(wm & lt)] = (int)mi;
            wbase += (unsigned)__popcll(wm);
            bool tk = (vb == Ts);
            unsigned long long tm2 = __ballot(tk);
            if (tk) {
                unsigned tp = tbase + (unsigned)__popcll(tm2 & lt);
                if (tp < 64) tie_idx[w][tp] = mi;
            }
            tbase += (unsigned)__popcll(tm2);
        }
        unsigned tc = tbase > 64 ? 64 : tbase;
        if ((int)tc == need) {
            bool tk = (lane < (int)tc);
            unsigned mi2 = tk ? tie_idx[w][lane] : 0xFFFFFFFFu;
            tk = tk && (mi2 != dropIdx);
            unsigned long long m3 = __ballot(tk);
            if (tk) o[wbase + (unsigned)__popcll(m3 & lt)] = (int)mi2;
        } else if (lane == 0) {
            unsigned pos = wbase;
            for (int r = 0; r < need; ++r) {
                unsigned best = 0xFFFFFFFFu; int bj = 0;
                for (int j2 = 0; j2 < (int)tc; ++j2) {
                    unsigned mi = tie_idx[w][j2];
                    if (mi < best) { best = mi; bj = j2; }
                }
                tie_idx[w][bj] = 0xFFFFFFFFu;
                if (best != dropIdx) o[pos++] = (int)best;
            }
        }
    }
}

// ---------------- fused_mlp19: out = mean_k gelu(gelu(G[idx]+Q) @ W2 + b2) ----------
// mlp18 (68.4 us champion) + bank-conflict fix in the shuffle-free epilogue:
// obuf partials at quad*2048 + idx put the 4 quads of each element in the SAME bank
// (2048 % 32 == 0) -> 4-way conflict on every store (SQ_LDS_BANK_CONFLICT 524K).
// XOR-swizzle idx by quad<<3 (flip float-index bits 3-4): write banks become 2-way
// (free), reads invert the same XOR (b128 alignment preserved, bits 0-1 untouched).
__global__ __launch_bounds__(512, 3) void fused_mlp19(const _Float16* __restrict__ Gall,
                                                      const _Float16* __restrict__ Qall,
                                                      const int* __restrict__ knn_idx,
                                                      const _Float16* __restrict__ W2f,
                                                      const float* __restrict__ b2,
                                                      float* __restrict__ out) {
    __shared__ __align__(16) _Float16 w2s[16384];        // 32 KB: half of W2f / obuf
    __shared__ __align__(16) _Float16 gbuf[8][2][1024];  // 32 KB: per-wave G dbuf
    __shared__ __align__(16) _Float16 qbuf[8][512];      //  8 KB: per-wave Q rows
    const int t = threadIdx.x, w = t >> 6, lane = t & 63;
    const int quad = lane >> 4, l16 = lane & 15;

    const int lb = ((blockIdx.x & 7) << 8) | (blockIdx.x >> 3);

    const int q0 = lb * 16 + w * 2;
    const int b = q0 >> 10;
    const int nb0 = knn_idx[q0 * KNN + l16];
    const int nb1 = knn_idx[(q0 + 1) * KNN + l16];
    const _Float16* g0 = Gall + ((size_t)(b << 10) + nb0) * H2;
    const _Float16* g1 = Gall + ((size_t)(b << 10) + nb1) * H2;

    // per-lane byte addresses
    const char* aG0 = (const char*)g0 + quad * 16;
    const char* aG1 = (const char*)g1 + quad * 16;
    const char* aQ  = (const char*)(Qall + (size_t)q0 * H2) + (lane >> 5) * (H2 * 2) + (lane & 31) * 16;
    const char* w2b = (const char*)W2f;

    // ---- prologue: stage Q (1 instr), W2f half0 (4), G pairs rk0/rk1 (4) ----
    gld16(aQ, &qbuf[w][0]);
#pragma unroll
    for (int i = 0; i < 4; ++i)
        gld16(w2b + i * 8192 + w * 1024 + lane * 16, &w2s[i * 4096 + w * 512]);
    gld16(aG0,      &gbuf[w][0][0]);
    gld16(aG1,      &gbuf[w][0][512]);
    gld16(aG0 + 64, &gbuf[w][1][0]);
    gld16(aG1 + 64, &gbuf[w][1][512]);

    f32x4 acc[2][8];
#pragma unroll
    for (int tm = 0; tm < 2; ++tm)
#pragma unroll
        for (int nt = 0; nt < 8; ++nt) acc[tm][nt] = (f32x4){0.f, 0.f, 0.f, 0.f};

    __syncthreads();   // drains all prologue loads (vmcnt(0) implied)

#define STEP(RK, WN)                                                                   \
    {                                                                                  \
        asm volatile("s_waitcnt vmcnt(%c0)" ::"i"(WN) : "memory");                     \
        f16x8 gA = *(const f16x8*)&gbuf[w][(RK) & 1][lane * 8];                        \
        f16x8 gB = *(const f16x8*)&gbuf[w][(RK) & 1][512 + lane * 8];                  \
        f16x8 qA = *(const f16x8*)&qbuf[w][(RK) * 32 + quad * 8];                      \
        f16x8 qB = *(const f16x8*)&qbuf[w][256 + (RK) * 32 + quad * 8];                \
        if ((RK) < 6) {                                                                \
            gld16(aG0 + ((RK) + 2) * 64, &gbuf[w][(RK) & 1][0]);                       \
            gld16(aG1 + ((RK) + 2) * 64, &gbuf[w][(RK) & 1][512]);                     \
        }                                                                              \
        f16x8 a0 = act8(gA, qA);                                                       \
        f16x8 a1 = act8(gB, qB);                                                       \
        const _Float16* bb = &w2s[((RK) & 3) * 4096 + lane * 8];                       \
        _Pragma("unroll")                                                              \
        for (int nt = 0; nt < 8; ++nt) {                                               \
            f16x8 bf = *(const f16x8*)(bb + nt * 512);                                 \
            acc[0][nt] = __builtin_amdgcn_mfma_f32_16x16x32_f16(a0, bf, acc[0][nt], 0, 0, 0); \
            acc[1][nt] = __builtin_amdgcn_mfma_f32_16x16x32_f16(a1, bf, acc[1][nt], 0, 0, 0); \
        }                                                                              \
    }

    STEP(0, 2) STEP(1, 2) STEP(2, 2) STEP(3, 2)

    // ---- mid-phase: swap in W2f half1 (barriers drain in-flight prefetches) ----
    __syncthreads();
#pragma unroll
    for (int i = 0; i < 4; ++i)
        gld16(w2b + 32768 + i * 8192 + w * 1024 + lane * 16, &w2s[i * 4096 + w * 512]);
    __syncthreads();

    STEP(4, 2) STEP(5, 2) STEP(6, 2) STEP(7, 0)
#undef STEP

    // ---- shuffle-free epilogue, XOR-swizzled: partials at quad*2048 + (idx^(quad<<3)) ----
    __syncthreads();
    float* obuf = (float*)w2s;       // 4 * 2048 * 4B = 32 KB exact
#pragma unroll
    for (int tm = 0; tm < 2; ++tm)
#pragma unroll
        for (int nt = 0; nt < 8; ++nt) {
            const float bias = b2[nt * 16 + l16];
            float s = gelu4_sum(acc[tm][nt], bias);
            const int idx = (w * 2 + tm) * 128 + nt * 16 + l16;
            obuf[quad * 2048 + (idx ^ (quad << 3))] = s;
        }
    __syncthreads();
    {
        // block covers queries [lb*16, lb*16+16): sum 4 quad-partials (inverting the
        // XOR per quad row -- bits 0-1 untouched so f32x4 alignment holds), store 16B.
        const int e = t * 4;
        f32x4 v0 = *(const f32x4*)&obuf[0 * 2048 + (e ^ 0)];
        f32x4 v1 = *(const f32x4*)&obuf[1 * 2048 + (e ^ 8)];
        f32x4 v2 = *(const f32x4*)&obuf[2 * 2048 + (e ^ 16)];
        f32x4 v3 = *(const f32x4*)&obuf[3 * 2048 + (e ^ 24)];
        f32x4 vs = ((v0 + v1) + (v2 + v3)) * 0.0625f;
        *(f32x4*)(out + (size_t)lb * 2048 + e) = vs;
    }
}

extern "C" void kernel_launch(void* const* d_in, const int* in_sizes, int n_in,
                              void* d_out, int out_size, void* d_ws, size_t ws_size,
                              hipStream_t stream) {
    const float* points   = (const float*)d_in[0];
    const float* features = (const float*)d_in[1];
    const float* W1 = (const float*)d_in[2];
    const float* b1 = (const float*)d_in[3];
    const float* W2 = (const float*)d_in[4];
    const float* b2 = (const float*)d_in[5];
    float* out = (float*)d_out;

    const size_t IDX_B  = (size_t)BB * NN * KNN * 4;   // 2 MB
    const size_t WCF_B  = 512 * 64 * 2;                // 64 KB
    const size_t W2F_B  = 256 * 128 * 2;               // 64 KB
    const size_t G_B    = (size_t)BB * NN * H2 * 2;    // 16 MB

    int* knn_idx = (int*)d_ws;
    char* p = (char*)d_ws + IDX_B;
    _Float16* Wcf  = (_Float16*)p;  p += WCF_B;
    _Float16* W2f  = (_Float16*)p;  p += W2F_B;
    _Float16* Gall = (_Float16*)p;  p += G_B;
    _Float16* Qall = (_Float16*)p;                     // 16 MB -> total ~34.1 MB

    prep_weights<<<16, 512, 0, stream>>>(W1, W2, Wcf, W2f);
    knn_gq<<<3072, 512, 0, stream>>>(points, knn_idx, features, Wcf, b1, Gall, Qall);
    fused_mlp19<<<2048, 512, 0, stream>>>(Gall, Qall, knn_idx, W2f, b2, out);
}